// Round 1
// baseline (453.847 us; speedup 1.0000x reference)
//
#include <hip/hip_runtime.h>
#include <stdint.h>

#define L_SEQ 2048
#define D_MODEL 1024
#define NHEAD 16
#define HS 64
#define B_BATCH 2

typedef __bf16 bf16x8 __attribute__((ext_vector_type(8)));
typedef float f32x4 __attribute__((ext_vector_type(4)));

__device__ __forceinline__ unsigned short f2b(float f) {
  unsigned int u = __float_as_uint(f);
  u += 0x7fffu + ((u >> 16) & 1u);
  return (unsigned short)(u >> 16);
}
__device__ __forceinline__ float b2f(unsigned short s) {
  return __uint_as_float(((unsigned int)s) << 16);
}

union U8 { uint4 v; unsigned short s[8]; };

__global__ __launch_bounds__(256) void cast_f32_to_bf16(const float* __restrict__ src,
                                                        unsigned short* __restrict__ dst,
                                                        int n) {
  int i = blockIdx.x * 256 + threadIdx.x;
  if (i < n) dst[i] = f2b(src[i]);
}

// C = A(MxK) * B(KxN) + bias, A/B bf16 row-major in global; B transposed into LDS
// during staging. MODE 0: scatter into q/k/v (B,H,L,HS) bf16. MODE 1: f32 out.
template <int MODE>
__global__ __launch_bounds__(256) void gemm_bf16(const unsigned short* __restrict__ A,
                                                 const unsigned short* __restrict__ Bw,
                                                 const float* __restrict__ bias,
                                                 void* __restrict__ out0,
                                                 unsigned short* __restrict__ kbuf,
                                                 unsigned short* __restrict__ vbuf,
                                                 int M, int N, int K) {
  __shared__ unsigned short As[128][72];
  __shared__ unsigned short Bs[128][72];
  const int tid = threadIdx.x;
  const int lane = tid & 63;
  const int w = tid >> 6;
  const int wm = w >> 1, wn = w & 1;
  const int quad = lane >> 4, lc = lane & 15;
  const int bm = blockIdx.y, bn = blockIdx.x;

  f32x4 zero4 = {0.f, 0.f, 0.f, 0.f};
  f32x4 acc[4][4];
#pragma unroll
  for (int mb = 0; mb < 4; mb++)
#pragma unroll
    for (int nb = 0; nb < 4; nb++) acc[mb][nb] = zero4;

  for (int kk = 0; kk < K; kk += 64) {
    if (kk) __syncthreads();
    // Stage A tile: 128 rows x 64 cols
#pragma unroll
    for (int i = 0; i < 4; i++) {
      int cid = i * 256 + tid;
      int r = cid >> 3, c8 = (cid & 7) << 3;
      *(uint4*)(&As[r][c8]) =
          *(const uint4*)(A + (size_t)(bm * 128 + r) * K + kk + c8);
    }
    // Stage B tile transposed: Bs[n_local][k_local]
#pragma unroll
    for (int i = 0; i < 4; i++) {
      int cid = i * 256 + tid;
      int kr = cid >> 4, nc8 = (cid & 15) << 3;
      U8 u;
      u.v = *(const uint4*)(Bw + (size_t)(kk + kr) * N + bn * 128 + nc8);
#pragma unroll
      for (int j = 0; j < 8; j++) Bs[nc8 + j][kr] = u.s[j];
    }
    __syncthreads();
#pragma unroll
    for (int ks = 0; ks < 2; ks++) {
      const int ko = ks * 32 + quad * 8;
      bf16x8 af[4], bfv[4];
#pragma unroll
      for (int mb = 0; mb < 4; mb++)
        af[mb] = *(const bf16x8*)(&As[wm * 64 + mb * 16 + lc][ko]);
#pragma unroll
      for (int nb = 0; nb < 4; nb++)
        bfv[nb] = *(const bf16x8*)(&Bs[wn * 64 + nb * 16 + lc][ko]);
#pragma unroll
      for (int mb = 0; mb < 4; mb++)
#pragma unroll
        for (int nb = 0; nb < 4; nb++)
          acc[mb][nb] = __builtin_amdgcn_mfma_f32_16x16x32_bf16(
              af[mb], bfv[nb], acc[mb][nb], 0, 0, 0);
    }
  }

#pragma unroll
  for (int nb = 0; nb < 4; nb++) {
    const int n = bn * 128 + wn * 64 + nb * 16 + lc;
    const float bv = bias[n];
#pragma unroll
    for (int mb = 0; mb < 4; mb++) {
#pragma unroll
      for (int reg = 0; reg < 4; reg++) {
        const int m = bm * 128 + wm * 64 + mb * 16 + quad * 4 + reg;
        float val = acc[mb][nb][reg] + bv;
        if (MODE == 0) {
          int which = n >> 10;
          int rem = n & 1023;
          int h = rem >> 6, d = rem & 63;
          int b = m >> 11, l = m & 2047;
          unsigned short* dst =
              which == 0 ? (unsigned short*)out0 : (which == 1 ? kbuf : vbuf);
          dst[((size_t)(b * NHEAD + h) * L_SEQ + l) * HS + d] = f2b(val);
        } else {
          ((float*)out0)[(size_t)m * N + n] = val;
        }
      }
    }
  }
}

// Flash attention with relative-position skew.
// Srel[q,k] = q . Er[L-1-q+k]  (k<=q), derived from the skew() reshape trick.
__global__ __launch_bounds__(256) void flash_attn_rel(
    const unsigned short* __restrict__ qb, const unsigned short* __restrict__ kb,
    const unsigned short* __restrict__ vb, const unsigned short* __restrict__ erb,
    unsigned short* __restrict__ yb) {
  __shared__ unsigned short Qs[64][72];
  __shared__ unsigned short Ks[64][72];
  __shared__ unsigned short Vt[64][72];   // Vt[dim][key]
  __shared__ unsigned short Es[128][72];  // Er band; reused as Ts[64][132] bf16
  __shared__ unsigned short Ps[64][72];

  const int tid = threadIdx.x;
  const int lane = tid & 63;
  const int w = tid >> 6;
  const int quad = lane >> 4, lc = lane & 15;
  const int bh = blockIdx.x;       // b*16 + h
  const int q0 = blockIdx.y * 64;  // q tile start
  const size_t head_off = (size_t)bh * L_SEQ * HS;

  // Stage Q tile (64x64)
#pragma unroll
  for (int i = 0; i < 2; i++) {
    int cid = i * 256 + tid;
    int r = cid >> 3, c8 = (cid & 7) << 3;
    *(uint4*)(&Qs[r][c8]) =
        *(const uint4*)(qb + head_off + (size_t)(q0 + r) * HS + c8);
  }

  f32x4 zero4 = {0.f, 0.f, 0.f, 0.f};
  f32x4 Oacc[4];
#pragma unroll
  for (int nb = 0; nb < 4; nb++) Oacc[nb] = zero4;
  float mrow[4], lrow[4];
#pragma unroll
  for (int r = 0; r < 4; r++) {
    mrow[r] = -1e30f;
    lrow[r] = 0.0f;
  }
  unsigned short* Ts = &Es[0][0];

  for (int k0 = 0; k0 <= q0; k0 += 64) {
    __syncthreads();
    // Stage K tile
#pragma unroll
    for (int i = 0; i < 2; i++) {
      int cid = i * 256 + tid;
      int r = cid >> 3, c8 = (cid & 7) << 3;
      *(uint4*)(&Ks[r][c8]) =
          *(const uint4*)(kb + head_off + (size_t)(k0 + r) * HS + c8);
    }
    // Stage V tile transposed
#pragma unroll
    for (int i = 0; i < 2; i++) {
      int cid = i * 256 + tid;
      int r = cid >> 3, c8 = (cid & 7) << 3;
      U8 u;
      u.v = *(const uint4*)(vb + head_off + (size_t)(k0 + r) * HS + c8);
#pragma unroll
      for (int j = 0; j < 8; j++) Vt[c8 + j][r] = u.s[j];
    }
    // Stage Er band: rows e0 .. e0+127 (>=L -> zeros, those are masked anyway)
    const int e0 = (L_SEQ - 64) - q0 + k0;
#pragma unroll
    for (int i = 0; i < 4; i++) {
      int cid = i * 256 + tid;
      int r = cid >> 3, c8 = (cid & 7) << 3;
      int e = e0 + r;
      uint4 val;
      if (e < L_SEQ)
        val = *(const uint4*)(erb + (size_t)e * HS + c8);
      else
        val = make_uint4(0u, 0u, 0u, 0u);
      *(uint4*)(&Es[r][c8]) = val;
    }
    __syncthreads();

    // S = Q K^T (4 nblocks), T = Q ErBand^T (8 nblocks)
    f32x4 sacc[4], tacc[8];
#pragma unroll
    for (int nb = 0; nb < 4; nb++) sacc[nb] = zero4;
#pragma unroll
    for (int nb = 0; nb < 8; nb++) tacc[nb] = zero4;
#pragma unroll
    for (int ks = 0; ks < 2; ks++) {
      const int ko = ks * 32 + quad * 8;
      bf16x8 aq = *(const bf16x8*)(&Qs[w * 16 + lc][ko]);
#pragma unroll
      for (int nb = 0; nb < 4; nb++) {
        bf16x8 bk = *(const bf16x8*)(&Ks[nb * 16 + lc][ko]);
        sacc[nb] =
            __builtin_amdgcn_mfma_f32_16x16x32_bf16(aq, bk, sacc[nb], 0, 0, 0);
      }
#pragma unroll
      for (int nb = 0; nb < 8; nb++) {
        bf16x8 be = *(const bf16x8*)(&Es[nb * 16 + lc][ko]);
        tacc[nb] =
            __builtin_amdgcn_mfma_f32_16x16x32_bf16(aq, be, tacc[nb], 0, 0, 0);
      }
    }
    __syncthreads();  // all Es reads complete before overwriting with Ts
#pragma unroll
    for (int nb = 0; nb < 8; nb++)
#pragma unroll
      for (int reg = 0; reg < 4; reg++)
        Ts[(w * 16 + quad * 4 + reg) * 132 + nb * 16 + lc] = f2b(tacc[nb][reg]);
    __syncthreads();  // Ts visible

    const bool diag = (k0 == q0);
    float alpha[4];
#pragma unroll
    for (int reg = 0; reg < 4; reg++) {
      const int row = quad * 4 + reg;   // row within wave's 16 q rows
      const int qlocal = w * 16 + row;  // row within 64-row q tile
      float s[4];
#pragma unroll
      for (int nb = 0; nb < 4; nb++) {
        const int ki = nb * 16 + lc;
        const int col = 63 - qlocal + ki;  // in [0,126]
        float t = b2f(Ts[qlocal * 132 + col]);
        float v = (sacc[nb][reg] + t) * 0.125f;
        if (diag && ki > qlocal) v = -1e30f;
        s[nb] = v;
      }
      float mx = fmaxf(fmaxf(s[0], s[1]), fmaxf(s[2], s[3]));
#pragma unroll
      for (int off = 1; off < 16; off <<= 1) mx = fmaxf(mx, __shfl_xor(mx, off, 64));
      const float mnew = fmaxf(mrow[reg], mx);
      float psum = 0.0f;
#pragma unroll
      for (int nb = 0; nb < 4; nb++) {
        float p = __expf(s[nb] - mnew);
        psum += p;
        Ps[qlocal][nb * 16 + lc] = f2b(p);
      }
#pragma unroll
      for (int off = 1; off < 16; off <<= 1) psum += __shfl_xor(psum, off, 64);
      alpha[reg] = __expf(mrow[reg] - mnew);
      lrow[reg] = lrow[reg] * alpha[reg] + psum;
      mrow[reg] = mnew;
    }
#pragma unroll
    for (int nb = 0; nb < 4; nb++)
#pragma unroll
      for (int reg = 0; reg < 4; reg++) Oacc[nb][reg] *= alpha[reg];
    __syncthreads();  // Ps visible (cheap safety; all waves uniform)

    // O += P V  (A-frag from Ps, B-frag from Vt)
#pragma unroll
    for (int ks = 0; ks < 2; ks++) {
      const int ko = ks * 32 + quad * 8;
      bf16x8 ap = *(const bf16x8*)(&Ps[w * 16 + lc][ko]);
#pragma unroll
      for (int nb = 0; nb < 4; nb++) {
        bf16x8 bv = *(const bf16x8*)(&Vt[nb * 16 + lc][ko]);
        Oacc[nb] =
            __builtin_amdgcn_mfma_f32_16x16x32_bf16(ap, bv, Oacc[nb], 0, 0, 0);
      }
    }
  }

  // Normalize and store y (B, L, D) bf16
  const int b = bh >> 4, h = bh & 15;
#pragma unroll
  for (int nb = 0; nb < 4; nb++) {
#pragma unroll
    for (int reg = 0; reg < 4; reg++) {
      const int qg = q0 + w * 16 + quad * 4 + reg;
      const int dcol = h * HS + nb * 16 + lc;
      float o = Oacc[nb][reg] / lrow[reg];
      yb[(size_t)(b * L_SEQ + qg) * D_MODEL + dcol] = f2b(o);
    }
  }
}

extern "C" void kernel_launch(void* const* d_in, const int* in_sizes, int n_in,
                              void* d_out, int out_size, void* d_ws, size_t ws_size,
                              hipStream_t stream) {
  const float* x = (const float*)d_in[0];
  const float* W_attn = (const float*)d_in[1];
  const float* b_attn = (const float*)d_in[2];
  const float* W_proj = (const float*)d_in[3];
  const float* b_proj = (const float*)d_in[4];
  const float* Er = (const float*)d_in[5];
  float* out = (float*)d_out;

  const int n_x = B_BATCH * L_SEQ * D_MODEL;        // 4,194,304
  const int n_wa = D_MODEL * 3 * D_MODEL;           // 3,145,728
  const int n_wp = D_MODEL * D_MODEL;               // 1,048,576
  const int n_er = L_SEQ * HS;                      // 131,072
  const int n_head = B_BATCH * NHEAD * L_SEQ * HS;  // 4,194,304

  unsigned short* xb = (unsigned short*)d_ws;
  unsigned short* wab = xb + n_x;
  unsigned short* wpb = wab + n_wa;
  unsigned short* erb = wpb + n_wp;
  unsigned short* qbuf = erb + n_er;
  unsigned short* kbuf = qbuf + n_head;
  unsigned short* vbuf = kbuf + n_head;
  unsigned short* ybuf = vbuf + n_head;  // (B*L, D) bf16

  cast_f32_to_bf16<<<(n_x + 255) / 256, 256, 0, stream>>>(x, xb, n_x);
  cast_f32_to_bf16<<<(n_wa + 255) / 256, 256, 0, stream>>>(W_attn, wab, n_wa);
  cast_f32_to_bf16<<<(n_wp + 255) / 256, 256, 0, stream>>>(W_proj, wpb, n_wp);
  cast_f32_to_bf16<<<(n_er + 255) / 256, 256, 0, stream>>>(Er, erb, n_er);

  // QKV: (4096 x 3072) = x(4096x1024) @ W_attn(1024x3072)
  gemm_bf16<0><<<dim3(24, 32), 256, 0, stream>>>(xb, wab, b_attn, qbuf, kbuf,
                                                 vbuf, B_BATCH * L_SEQ,
                                                 3 * D_MODEL, D_MODEL);

  // Flash attention with relative positions
  flash_attn_rel<<<dim3(B_BATCH * NHEAD, L_SEQ / 64), 256, 0, stream>>>(
      qbuf, kbuf, vbuf, erb, ybuf);

  // Output projection: out(4096x1024) = y(4096x1024) @ W_proj(1024x1024)
  gemm_bf16<1><<<dim3(8, 32), 256, 0, stream>>>(ybuf, wpb, b_proj, out, nullptr,
                                                nullptr, B_BATCH * L_SEQ,
                                                D_MODEL, D_MODEL);
}

// Round 2
// 239.450 us; speedup vs baseline: 1.8954x; 1.8954x over previous
//
#include <hip/hip_runtime.h>
#include <stdint.h>

#define L_SEQ 2048
#define D_MODEL 1024
#define NHEAD 16
#define HS 64
#define B_BATCH 2

typedef __bf16 bf16x8 __attribute__((ext_vector_type(8)));
typedef float f32x4 __attribute__((ext_vector_type(4)));

__device__ __forceinline__ unsigned short f2b(float f) {
  unsigned int u = __float_as_uint(f);
  u += 0x7fffu + ((u >> 16) & 1u);
  return (unsigned short)(u >> 16);
}
__device__ __forceinline__ float b2f(unsigned short s) {
  return __uint_as_float(((unsigned int)s) << 16);
}
__device__ __forceinline__ unsigned int pk2(float a, float b) {
  return (unsigned int)f2b(a) | ((unsigned int)f2b(b) << 16);
}

union U8 { uint4 v; unsigned short s[8]; };

// async global->LDS, 16B per lane, dest = wave-uniform base + lane*16
__device__ __forceinline__ void ldsload16(const unsigned short* g, unsigned short* l) {
  __builtin_amdgcn_global_load_lds(
      (const __attribute__((address_space(1))) unsigned int*)g,
      (__attribute__((address_space(3))) unsigned int*)l, 16, 0, 0);
}

// swizzled frag read: rows are 64 shorts (128B) unpadded; 16B unit index is
// XORed with (row&7) so 16 consecutive rows spread over all banks.
__device__ __forceinline__ bf16x8 frag_ld(const unsigned short* base, int row, int ks, int quad) {
  const int unit = (ks * 4 + quad) ^ (row & 7);
  return *(const bf16x8*)(base + row * 64 + unit * 8);
}

__global__ __launch_bounds__(256) void cast8(const float* __restrict__ s,
                                             unsigned short* __restrict__ d, int n8) {
  int i = blockIdx.x * 256 + threadIdx.x;
  if (i >= n8) return;
  const float4* s4 = (const float4*)s;
  float4 a = s4[i * 2], b = s4[i * 2 + 1];
  U8 u;
  u.s[0] = f2b(a.x); u.s[1] = f2b(a.y); u.s[2] = f2b(a.z); u.s[3] = f2b(a.w);
  u.s[4] = f2b(b.x); u.s[5] = f2b(b.y); u.s[6] = f2b(b.z); u.s[7] = f2b(b.w);
  ((uint4*)d)[i] = u.v;
}

// Er cast with 64 zero rows of padding at the end (band staging reads past L).
__global__ __launch_bounds__(256) void cast_er(const float* __restrict__ s,
                                               unsigned short* __restrict__ d,
                                               int n, int ntot) {
  int i = blockIdx.x * 256 + threadIdx.x;
  if (i < ntot) d[i] = (i < n) ? f2b(s[i]) : (unsigned short)0;
}

// dst[n][k] = bf16(src[k][n]); src f32 KxN row-major.
__global__ __launch_bounds__(256) void transpose_cast(const float* __restrict__ src,
                                                      unsigned short* __restrict__ dst,
                                                      int K, int N) {
  __shared__ unsigned short tt[64][65];
  const int n0 = blockIdx.x * 64, k0 = blockIdx.y * 64;
  const int c = threadIdx.x & 63, r0 = threadIdx.x >> 6;
#pragma unroll
  for (int i = 0; i < 16; i++) {
    int r = r0 * 16 + i;
    tt[r][c] = f2b(src[(size_t)(k0 + r) * N + n0 + c]);
  }
  __syncthreads();
  const int n = threadIdx.x >> 2, ks = (threadIdx.x & 3) * 16;
  U8 u0, u1;
#pragma unroll
  for (int j = 0; j < 8; j++) {
    u0.s[j] = tt[ks + j][n];
    u1.s[j] = tt[ks + 8 + j][n];
  }
  unsigned short* d = dst + (size_t)(n0 + n) * K + k0 + ks;
  *(uint4*)d = u0.v;
  *(uint4*)(d + 8) = u1.v;
}

// C = A(MxK) * B(KxN) + bias with Bt = B^T (NxK) row-major. m97-style:
// global_load_lds width-16 staging, 128x128 tile, BK=64, swizzled LDS.
// MODE 0: scatter into q/k/v (B,H,L,HS) bf16. MODE 1: f32 out.
template <int MODE>
__global__ __launch_bounds__(256, 3) void gemm_bt(
    const unsigned short* __restrict__ A, const unsigned short* __restrict__ Bt,
    const float* __restrict__ bias, void* __restrict__ out0,
    unsigned short* __restrict__ kbuf, unsigned short* __restrict__ vbuf,
    int M, int N, int K) {
  __shared__ unsigned short As[128 * 64];
  __shared__ unsigned short Bs[128 * 64];
  const int tid = threadIdx.x, lane = tid & 63, w = tid >> 6;
  const int wm = w >> 1, wn = w & 1, quad = lane >> 4, lc = lane & 15;
  const int bm = blockIdx.y, bn = blockIdx.x;
  const int l8 = lane >> 3, u8 = ((lane & 7) ^ l8) * 8;
  const unsigned short* Ab = A + (size_t)bm * 128 * K;
  const unsigned short* Bb = Bt + (size_t)bn * 128 * K;

  f32x4 z4 = {0.f, 0.f, 0.f, 0.f};
  f32x4 acc[4][4];
#pragma unroll
  for (int mb = 0; mb < 4; mb++)
#pragma unroll
    for (int nb = 0; nb < 4; nb++) acc[mb][nb] = z4;

  for (int kk = 0; kk < K; kk += 64) {
    if (kk) __syncthreads();
#pragma unroll
    for (int i = 0; i < 4; i++) {
      int ch = w * 4 + i;
      ldsload16(Ab + (size_t)(ch * 8 + l8) * K + kk + u8, &As[ch * 512]);
      ldsload16(Bb + (size_t)(ch * 8 + l8) * K + kk + u8, &Bs[ch * 512]);
    }
    __syncthreads();
#pragma unroll
    for (int ks = 0; ks < 2; ks++) {
      bf16x8 af[4], bfv[4];
#pragma unroll
      for (int mb = 0; mb < 4; mb++) af[mb] = frag_ld(As, wm * 64 + mb * 16 + lc, ks, quad);
#pragma unroll
      for (int nb = 0; nb < 4; nb++) bfv[nb] = frag_ld(Bs, wn * 64 + nb * 16 + lc, ks, quad);
#pragma unroll
      for (int mb = 0; mb < 4; mb++)
#pragma unroll
        for (int nb = 0; nb < 4; nb++)
          acc[mb][nb] = __builtin_amdgcn_mfma_f32_16x16x32_bf16(af[mb], bfv[nb],
                                                               acc[mb][nb], 0, 0, 0);
    }
  }

#pragma unroll
  for (int nb = 0; nb < 4; nb++) {
    const int n = bn * 128 + wn * 64 + nb * 16 + lc;
    const float bv = bias[n];
#pragma unroll
    for (int mb = 0; mb < 4; mb++) {
#pragma unroll
      for (int reg = 0; reg < 4; reg++) {
        const int m = bm * 128 + wm * 64 + mb * 16 + quad * 4 + reg;
        float val = acc[mb][nb][reg] + bv;
        if (MODE == 0) {
          int which = n >> 10;
          int rem = n & 1023;
          int h = rem >> 6, d = rem & 63;
          int b = m >> 11, l = m & 2047;
          unsigned short* dst =
              which == 0 ? (unsigned short*)out0 : (which == 1 ? kbuf : vbuf);
          dst[((size_t)(b * NHEAD + h) * L_SEQ + l) * HS + d] = f2b(val);
        } else {
          ((float*)out0)[(size_t)m * N + n] = val;
        }
      }
    }
  }
}

// Flash attention with relative positions, transposed-S formulation.
// Srel[q,k] = q . Er[L-1-q+k] (k<=q). Each wave owns 16 q rows (its MFMA
// column block): softmax reductions are 2 shuffles; P^T stays wave-private.
__global__ __launch_bounds__(256, 3) void flash_attn_rel(
    const unsigned short* __restrict__ qb, const unsigned short* __restrict__ kb,
    const unsigned short* __restrict__ vb, const unsigned short* __restrict__ erb,
    unsigned short* __restrict__ yb) {
  __shared__ unsigned short Ks[64 * 64];
  __shared__ unsigned short Es[128 * 64];  // Er band; reused as Yt[64][72] in epilogue
  __shared__ unsigned short Vt[64 * 72];   // V^T: Vt[d][k]
  __shared__ unsigned short Tw[4][16 * 88]; // per-wave: T^T then P^T, [q][.] stride 88

  const int tid = threadIdx.x, lane = tid & 63, w = tid >> 6;
  const int quad = lane >> 4, lc = lane & 15;
  const int bh = blockIdx.x;
  const int b = bh >> 4, h = bh & 15;
  const size_t hoff = (size_t)bh * L_SEQ * HS;
  unsigned short* Twm = Tw[w];
  const int l8 = lane >> 3, u8 = ((lane & 7) ^ l8) * 8;
  const f32x4 z4 = {0.f, 0.f, 0.f, 0.f};

  for (int phase = 0; phase < 2; phase++) {
    const int qt = (phase == 0) ? (int)blockIdx.y : 31 - (int)blockIdx.y;
    const int q0 = qt * 64;
    const int qg0 = q0 + w * 16;  // wave's first q row

    bf16x8 qf[2];
    {
      const unsigned short* qrow = qb + hoff + (size_t)(qg0 + lc) * HS;
      qf[0] = *(const bf16x8*)(qrow + quad * 8);
      qf[1] = *(const bf16x8*)(qrow + 32 + quad * 8);
    }
    f32x4 Oacc[4];
#pragma unroll
    for (int db = 0; db < 4; db++) Oacc[db] = z4;
    float mrow = -1e30f, lrow = 0.0f;

    for (int k0 = 0; k0 <= q0; k0 += 64) {
      __syncthreads();
      // --- stage K (global_load_lds), Er band (global_load_lds), V^T (manual) ---
      {
        const unsigned short* kg = kb + hoff + (size_t)k0 * HS;
#pragma unroll
        for (int i = 0; i < 2; i++) {
          int ch = w * 2 + i;
          ldsload16(kg + (size_t)(ch * 8 + l8) * HS + u8, &Ks[ch * 512]);
        }
        const int e0b = (L_SEQ - 64) - q0 + k0;  // >= 0 always
        const unsigned short* eg = erb + (size_t)e0b * HS;
#pragma unroll
        for (int i = 0; i < 4; i++) {
          int ch = w * 4 + i;
          ldsload16(eg + (size_t)(ch * 8 + l8) * HS + u8, &Es[ch * 512]);
        }
        const unsigned short* vg = vb + hoff + (size_t)k0 * HS;
#pragma unroll
        for (int i = 0; i < 2; i++) {
          int c8 = (i * 4 + w) * 8;
          U8 uu;
          uu.v = *(const uint4*)(vg + (size_t)lane * HS + c8);
#pragma unroll
          for (int j = 0; j < 8; j++) Vt[(c8 + j) * 72 + lane] = uu.s[j];
        }
      }
      __syncthreads();

      if (k0 > qg0 + 15) continue;  // tile fully masked for this wave

      // --- S^T = K Q^T (4 blocks), T^T = ErBand Q^T (5 blocks) ---
      f32x4 sacc[4], tacc[5];
#pragma unroll
      for (int i = 0; i < 4; i++) sacc[i] = z4;
#pragma unroll
      for (int i = 0; i < 5; i++) tacc[i] = z4;
      const int ebw = 48 - w * 16;  // wave's band start within Es
#pragma unroll
      for (int ks = 0; ks < 2; ks++) {
#pragma unroll
        for (int kbi = 0; kbi < 4; kbi++) {
          bf16x8 a = frag_ld(Ks, kbi * 16 + lc, ks, quad);
          sacc[kbi] = __builtin_amdgcn_mfma_f32_16x16x32_bf16(a, qf[ks], sacc[kbi], 0, 0, 0);
        }
#pragma unroll
        for (int eb = 0; eb < 5; eb++) {
          bf16x8 a = frag_ld(Es, ebw + eb * 16 + lc, ks, quad);
          tacc[eb] = __builtin_amdgcn_mfma_f32_16x16x32_bf16(a, qf[ks], tacc[eb], 0, 0, 0);
        }
      }
      // T^T -> wave-private LDS: Twm[q=lc][e], e = eb*16+quad*4+reg in [0,80)
#pragma unroll
      for (int eb = 0; eb < 5; eb++) {
        uint2 pk;
        pk.x = pk2(tacc[eb][0], tacc[eb][1]);
        pk.y = pk2(tacc[eb][2], tacc[eb][3]);
        *(uint2*)&Twm[lc * 88 + eb * 16 + quad * 4] = pk;
      }
      asm volatile("" ::: "memory");

      // --- softmax over this k-tile (lane owns q=qg0+lc, k=quad*4+reg per kb) ---
      const bool domask = (k0 + 63) > qg0;
      float s[4][4];
#pragma unroll
      for (int kbi = 0; kbi < 4; kbi++) {
#pragma unroll
        for (int reg = 0; reg < 4; reg++) {
          float t = b2f(Twm[lc * 88 + (15 - lc) + kbi * 16 + quad * 4 + reg]);
          float v = (sacc[kbi][reg] + t) * 0.125f;
          if (domask && (k0 + kbi * 16 + quad * 4 + reg) > (qg0 + lc)) v = -1e30f;
          s[kbi][reg] = v;
        }
      }
      float mx = -1e30f;
#pragma unroll
      for (int kbi = 0; kbi < 4; kbi++)
#pragma unroll
        for (int reg = 0; reg < 4; reg++) mx = fmaxf(mx, s[kbi][reg]);
      mx = fmaxf(mx, __shfl_xor(mx, 16, 64));
      mx = fmaxf(mx, __shfl_xor(mx, 32, 64));
      const float mnew = fmaxf(mrow, mx);
      float p[4][4], psum = 0.0f;
#pragma unroll
      for (int kbi = 0; kbi < 4; kbi++)
#pragma unroll
        for (int reg = 0; reg < 4; reg++) {
          p[kbi][reg] = __expf(s[kbi][reg] - mnew);
          psum += p[kbi][reg];
        }
      psum += __shfl_xor(psum, 16, 64);
      psum += __shfl_xor(psum, 32, 64);
      const float alpha = __expf(mrow - mnew);
      lrow = lrow * alpha + psum;
      mrow = mnew;
#pragma unroll
      for (int db = 0; db < 4; db++) Oacc[db] *= alpha;
      // P^T -> same wave-private LDS region: Twm[q=lc][k]
#pragma unroll
      for (int kbi = 0; kbi < 4; kbi++) {
        uint2 pk;
        pk.x = pk2(p[kbi][0], p[kbi][1]);
        pk.y = pk2(p[kbi][2], p[kbi][3]);
        *(uint2*)&Twm[lc * 88 + kbi * 16 + quad * 4] = pk;
      }
      asm volatile("" ::: "memory");

      // --- O^T += V^T P^T ---
#pragma unroll
      for (int ks = 0; ks < 2; ks++) {
        bf16x8 pf = *(const bf16x8*)&Twm[lc * 88 + ks * 32 + quad * 8];
#pragma unroll
        for (int db = 0; db < 4; db++) {
          bf16x8 av = *(const bf16x8*)&Vt[(db * 16 + lc) * 72 + ks * 32 + quad * 8];
          Oacc[db] = __builtin_amdgcn_mfma_f32_16x16x32_bf16(av, pf, Oacc[db], 0, 0, 0);
        }
      }
    }

    // --- epilogue: O^T/l -> LDS transpose -> coalesced global store ---
    __syncthreads();
    const float inv = 1.0f / lrow;
    unsigned short* Yt = Es;  // reuse as [64][72]
#pragma unroll
    for (int db = 0; db < 4; db++) {
      uint2 pk;
      pk.x = pk2(Oacc[db][0] * inv, Oacc[db][1] * inv);
      pk.y = pk2(Oacc[db][2] * inv, Oacc[db][3] * inv);
      *(uint2*)&Yt[(w * 16 + lc) * 72 + db * 16 + quad * 4] = pk;
    }
    __syncthreads();
    {
      const int r = tid >> 2, seg = (tid & 3) * 16;
      uint4 a0 = *(const uint4*)&Yt[r * 72 + seg];
      uint4 a1 = *(const uint4*)&Yt[r * 72 + seg + 8];
      unsigned short* d = yb + (size_t)((size_t)b * L_SEQ + q0 + r) * D_MODEL + h * HS + seg;
      *(uint4*)d = a0;
      *(uint4*)(d + 8) = a1;
    }
  }
}

extern "C" void kernel_launch(void* const* d_in, const int* in_sizes, int n_in,
                              void* d_out, int out_size, void* d_ws, size_t ws_size,
                              hipStream_t stream) {
  const float* x = (const float*)d_in[0];
  const float* W_attn = (const float*)d_in[1];
  const float* b_attn = (const float*)d_in[2];
  const float* W_proj = (const float*)d_in[3];
  const float* b_proj = (const float*)d_in[4];
  const float* Er = (const float*)d_in[5];
  float* out = (float*)d_out;

  const int n_x = B_BATCH * L_SEQ * D_MODEL;        // 4,194,304
  const int n_wa = D_MODEL * 3 * D_MODEL;           // 3,145,728
  const int n_wp = D_MODEL * D_MODEL;               // 1,048,576
  const int n_er = L_SEQ * HS;                      // 131,072
  const int n_er_pad = (L_SEQ + 64) * HS;           // +64 zero rows
  const int n_head = B_BATCH * NHEAD * L_SEQ * HS;  // 4,194,304

  unsigned short* xb = (unsigned short*)d_ws;
  unsigned short* wabT = xb + n_x;     // W_attn^T (3D x D) bf16
  unsigned short* wpbT = wabT + n_wa;  // W_proj^T (D x D) bf16
  unsigned short* erb = wpbT + n_wp;
  unsigned short* qbuf = erb + n_er_pad;
  unsigned short* kbuf = qbuf + n_head;
  unsigned short* vbuf = kbuf + n_head;
  unsigned short* ybuf = vbuf + n_head;  // (B*L, D) bf16

  cast8<<<(n_x / 8 + 255) / 256, 256, 0, stream>>>(x, xb, n_x / 8);
  transpose_cast<<<dim3(3 * D_MODEL / 64, D_MODEL / 64), 256, 0, stream>>>(
      W_attn, wabT, D_MODEL, 3 * D_MODEL);
  transpose_cast<<<dim3(D_MODEL / 64, D_MODEL / 64), 256, 0, stream>>>(
      W_proj, wpbT, D_MODEL, D_MODEL);
  cast_er<<<(n_er_pad + 255) / 256, 256, 0, stream>>>(Er, erb, n_er, n_er_pad);

  // QKV: (4096 x 3072) = x(4096x1024) @ W_attn(1024x3072)
  gemm_bt<0><<<dim3(24, 32), 256, 0, stream>>>(xb, wabT, b_attn, qbuf, kbuf,
                                               vbuf, B_BATCH * L_SEQ,
                                               3 * D_MODEL, D_MODEL);

  // Flash attention with relative positions; paired q-tiles {j, 31-j}
  flash_attn_rel<<<dim3(B_BATCH * NHEAD, 16), 256, 0, stream>>>(qbuf, kbuf,
                                                                vbuf, erb, ybuf);

  // Output projection: out(4096x1024) = y(4096x1024) @ W_proj(1024x1024)
  gemm_bt<1><<<dim3(8, 32), 256, 0, stream>>>(ybuf, wpbT, b_proj, out, nullptr,
                                              nullptr, B_BATCH * L_SEQ,
                                              D_MODEL, D_MODEL);
}